// Round 6
// baseline (3838.059 us; speedup 1.0000x reference)
//
#include <hip/hip_runtime.h>
#include <math.h>

// Problem constants (fixed by reference setup_inputs)
#define B   8
#define C   64
#define HH  192
#define WWD 192
#define P   (HH*WWD)     // 36864
#define NC  2
#define NS  8
#define PP  (194*194)    // padded space map (1-px zero halo), 37636

// Workspace layout (float offsets)
#define OFF_SPACE 0                    // 128 maps * PP = 4817408 (zero-padded)
// Wt and gmap REUSE the spp region (dead after k_R2): k_wt/k_g run after k_R2.
#define OFF_WT    0                    // 8*576*64 = 294912 transposed Wxs
#define OFF_GM    294912               // 8*2*P = 589824 combined attention maps
#define OFF_SPART 4817408              // 128*144 per-block S partials
#define OFF_R     4835840              // 8*16*64*9 = 73728 correlations (zeroed; k_R2 atomically accumulates)
#define OFF_TOK2  4909568              // 8*2*64 = 1024 (atomic accumulated, needs zero)
#define OFF_U     4910592              // 8*64*2*9 = 9216 collapsed conv weights
#define OFF_STP   4919808              // 2*64*288 BN partial sums ([slot][oc] major)
#define OFF_SCALE 4956672              // 64
#define OFF_SHIFT 4956736              // 64
#define WS_FLOATS 4956800              // ~19.8 MB total

__device__ __forceinline__ float sigm(float x) { return 1.0f / (1.0f + expf(-x)); }

// K1: space maps (sigmoid + 1->7 ch 3x3 conv + sigmoid) into zero-padded layout,
// plus per-(map,ch) per-block partial sums (NO global atomics).
__global__ void k_space(const float* __restrict__ cs, const float* __restrict__ Wc,
                        float* __restrict__ spp, float* __restrict__ Spart) {
    int m = blockIdx.y;                       // m = b*2 + c
    int bx = blockIdx.x;
    int p = bx * 256 + threadIdx.x;           // 144*256 == P exactly
    int h = p / WWD, w = p - (p / WWD) * WWD;
    float cp[9];
    #pragma unroll
    for (int ky = 0; ky < 3; ky++)
        #pragma unroll
        for (int kx = 0; kx < 3; kx++) {
            int hh = h + ky - 1, ww = w + kx - 1;
            float v = 0.f;  // zero-pad AFTER sigmoid (conv pads class_prob with 0)
            if ((unsigned)hh < HH && (unsigned)ww < WWD)
                v = sigm(cs[m * P + hh * WWD + ww]);
            cp[ky * 3 + kx] = v;
        }
    float ch[8];
    ch[0] = cp[4];
    #pragma unroll
    for (int j = 0; j < 7; j++) {
        float a = 0.f;
        #pragma unroll
        for (int k = 0; k < 9; k++) a += Wc[j * 9 + k] * cp[k];
        ch[j + 1] = sigm(a);
    }
    #pragma unroll
    for (int q = 0; q < 8; q++)
        spp[(m * 8 + q) * PP + (h + 1) * 194 + (w + 1)] = ch[q];
    // per-wave shfl reduce -> LDS -> per-block partial (no atomics)
    __shared__ float red[4][8];
    int lane = threadIdx.x & 63, wave = threadIdx.x >> 6;
    #pragma unroll
    for (int q = 0; q < 8; q++) {
        float v = ch[q];
        for (int off = 32; off > 0; off >>= 1) v += __shfl_down(v, off);
        if (lane == 0) red[wave][q] = v;
    }
    __syncthreads();
    if (threadIdx.x < 8) {
        int q = threadIdx.x;
        Spart[(m * 8 + q) * 144 + bx] = red[0][q] + red[1][q] + red[2][q] + red[3][q];
    }
}

// One correlation step: g loads + 288 FMAs for iteration `it` using x buffer xv.
__device__ __forceinline__ void fma_step(const float* __restrict__ sp, int it, int tid4,
                                         const float4 xv[8], float acc[8][9]) {
    int p0 = it * 1024 + tid4;
    int h = p0 / WWD, w0 = p0 - h * WWD;
    float g[3][6];
    #pragma unroll
    for (int ty = 0; ty < 3; ty++) {
        const float* rp = sp + (h + 2 - ty) * 194 + w0;
        float4 ga; float2 gb;
        __builtin_memcpy(&ga, rp, 16);
        __builtin_memcpy(&gb, rp + 4, 8);
        g[ty][0] = ga.x; g[ty][1] = ga.y; g[ty][2] = ga.z;
        g[ty][3] = ga.w; g[ty][4] = gb.x; g[ty][5] = gb.y;
    }
    #pragma unroll
    for (int ty = 0; ty < 3; ty++)
        #pragma unroll
        for (int tx = 0; tx < 3; tx++) {
            float g0 = g[ty][2 - tx], g1 = g[ty][3 - tx];
            float g2 = g[ty][4 - tx], g3 = g[ty][5 - tx];
            #pragma unroll
            for (int i = 0; i < 8; i++) {
                float a = acc[i][ty * 3 + tx];
                a += xv[i].x * g0; a += xv[i].y * g1;
                a += xv[i].z * g2; a += xv[i].w * g3;
                acc[i][ty * 3 + tx] = a;
            }
        }
}

// K2: register-tiled correlation, one space map x 8 x-channels per block.
// R5 diagnosis: VGPR=84 forces 3-4 load->wait->FMA phases per iter, each exposing
// L2/L3 latency (wall ~3100cy/iter vs ~650cy issue). FIX: unroll x2 with ping-pong
// x buffers (xa/xbf) + sched_barrier(0) fences pinning next-iter loads BEFORE the
// FMA block (rule 18: the fence, not "memory", stops hipcc sinking the loads).
// Live set: acc 72 + 2x32 xbuf + g 18 + addr ~12 = ~166 <= 170 cap at (256,3).
__launch_bounds__(256, 3)
__global__ void k_R2(const float* __restrict__ x, const float* __restrict__ spp,
                     float* __restrict__ R) {
    int ig = blockIdx.x;    // 0..7 : i = ig*8 + il
    int scz = blockIdx.y;   // 0..31 : sc = scz & 15, half = scz >> 4
    int b  = blockIdx.z;
    int sc = scz & 15;
    int half = scz >> 4;
    int s = sc >> 1, c = sc & 1;
    const float* xb = x + (b * C + ig * 8) * P;
    const float* sp = spp + ((b * NC + c) * NS + s) * PP;

    float acc[8][9];
    #pragma unroll
    for (int i = 0; i < 8; i++)
        #pragma unroll
        for (int t = 0; t < 9; t++) acc[i][t] = 0.f;

    const int it0 = half * 18;
    const int tid4 = threadIdx.x * 4;

    float4 xa[8], xp[8];
    {   // prologue: load iter it0 into A
        int p0 = it0 * 1024 + tid4;
        #pragma unroll
        for (int i = 0; i < 8; i++) xa[i] = *(const float4*)(xb + i * P + p0);
    }
    #pragma unroll
    for (int k = 0; k < 9; k++) {
        int itA = it0 + 2 * k;
        {   // issue loads for itA+1 into B
            int p1 = (itA + 1) * 1024 + tid4;
            #pragma unroll
            for (int i = 0; i < 8; i++) xp[i] = *(const float4*)(xb + i * P + p1);
        }
        __builtin_amdgcn_sched_barrier(0);
        fma_step(sp, itA, tid4, xa, acc);          // compute itA while B in flight
        {   // issue loads for itA+2 into A (last body reloads itA harmlessly)
            int pc = ((k < 8) ? (itA + 2) : itA) * 1024 + tid4;
            #pragma unroll
            for (int i = 0; i < 8; i++) xa[i] = *(const float4*)(xb + i * P + pc);
        }
        __builtin_amdgcn_sched_barrier(0);
        fma_step(sp, itA + 1, tid4, xp, acc);      // compute itA+1 while A in flight
    }

    __shared__ float red[4][72];
    int lane = threadIdx.x & 63, wave = threadIdx.x >> 6;
    #pragma unroll
    for (int i = 0; i < 8; i++)
        #pragma unroll
        for (int t = 0; t < 9; t++) {
            float v = acc[i][t];
            for (int off = 32; off > 0; off >>= 1) v += __shfl_down(v, off);
            if (lane == 0) red[wave][i * 9 + t] = v;
        }
    __syncthreads();
    if (threadIdx.x < 72) {
        int i = threadIdx.x / 9, t = threadIdx.x - (threadIdx.x / 9) * 9;
        float v = red[0][threadIdx.x] + red[1][threadIdx.x] +
                  red[2][threadIdx.x] + red[3][threadIdx.x];
        atomicAdd(&R[((b * 16 + sc) * 64 + (ig * 8 + i)) * 9 + t], v);
    }
}

// K2b: transpose Wxs into Wt[s][t][d] so k_tok2's weight reads are lane-coalesced.
// Runs AFTER k_R2 (Wt lives in the dead spp region). 1.2 MB, trivial.
__global__ void k_wt(const float* __restrict__ Wxs, float* __restrict__ Wt) {
    int t = blockIdx.x;   // 0..575
    int s = blockIdx.y;   // 0..7
    int d = threadIdx.x;  // 0..63
    Wt[(s * 576 + t) * 64 + d] = Wxs[(s * 64 + d) * 576 + t];
}

// K2c: combined attention map gmap[b][cl][p] = sum_s Wcomb[s]*Wcval[s]*sigm(sigm(cs)*Wattn[s])
// Computed ONCE per pixel (was recomputed 8x per ocg in k_cs AND k_fin2).
__global__ void k_g(const float* __restrict__ cs, const float* __restrict__ Wcval,
                    const float* __restrict__ Wattn, const float* __restrict__ Wcomb,
                    float* __restrict__ gmap) {
    int m = blockIdx.y;                       // b*2 + cl
    int p = blockIdx.x * 256 + threadIdx.x;   // 144*256 == P
    float wa[8], wt[8];
    #pragma unroll
    for (int s = 0; s < 8; s++) { wa[s] = Wcomb[s] * Wcval[s]; wt[s] = Wattn[s]; }
    float cp = sigm(cs[m * P + p]);
    float a = 0.f;
    #pragma unroll
    for (int s = 0; s < 8; s++) a += wa[s] * sigm(cp * wt[s]);
    gmap[m * P + p] = a;
}

// K3: tok2[b,c,d] = sum_s Wcs[s]/S[b,c,s] * sum_{t} Wt[s][t][d] * R[b,s,c,t]
// Wt transposed -> coalesced weight loads; R row is a broadcast (L1-served).
__global__ void k_tok2(const float* __restrict__ Wt, const float* __restrict__ Wcs,
                       const float* __restrict__ R, const float* __restrict__ Spart,
                       float* __restrict__ tok2) {
    int bc = blockIdx.x, s = blockIdx.y;
    int d = threadIdx.x;
    const float* spp = Spart + (bc * 8 + s) * 144;
    float sv = 0.f;
    for (int k = d; k < 144; k += 64) sv += spp[k];
    #pragma unroll
    for (int msk = 32; msk >= 1; msk >>= 1) sv += __shfl_xor(sv, msk);

    const float* Rp = R + ((bc & 1) + ((bc >> 1) * 16 + s * 2)) * 576;
    const float* Wp = Wt + s * 576 * 64 + d;
    float a = 0.f;
    #pragma unroll 4
    for (int t = 0; t < 576; t++) a += Wp[t * 64] * Rp[t];
    float val = a * Wcs[s] / sv;
    atomicAdd(&tok2[bc * C + d], val);   // 8K atomics over 1024 addrs — negligible
}

// K4: collapse conv weights against tok2:  U[b][oc][m][t] = sum_ci Ws[oc,ci,t] * tok2[b,m,ci]
__global__ void k_U(const float* __restrict__ Ws, const float* __restrict__ tok2,
                    float* __restrict__ U) {
    int b = blockIdx.x, m = blockIdx.y, oc = threadIdx.x;
    const float* tp = tok2 + (b * NC + m) * C;
    float u[9];
    #pragma unroll
    for (int t = 0; t < 9; t++) u[t] = 0.f;
    for (int ci = 0; ci < C; ci++) {
        float tv = tp[ci];
        const float* wp = Ws + (oc * C + ci) * 9;
        #pragma unroll
        for (int t = 0; t < 9; t++) u[t] += wp[t] * tv;
    }
    float* up = U + ((b * C + oc) * 2 + m) * 9;
    #pragma unroll
    for (int t = 0; t < 9; t++) up[t] = u[t];
}

// Shared staging: g0/g1 34x34 halo tiles from precomputed gmap (pure coalesced copy).
__device__ __forceinline__ void stage_g(const float* __restrict__ gmap, int b, int ty0, int tx0,
                                        float* h0, float* h1) {
    const float* g0p = gmap + (b * NC + 0) * P;
    const float* g1p = gmap + (b * NC + 1) * P;
    for (int idx = threadIdx.x; idx < 34 * 34; idx += 256) {
        int i = idx / 34, j = idx - (idx / 34) * 34;
        int gy = ty0 - 1 + i, gx = tx0 - 1 + j;
        float a0 = 0.f, a1 = 0.f;
        if ((unsigned)gy < HH && (unsigned)gx < WWD) {
            int p = gy * WWD + gx;
            a0 = g0p[p]; a1 = g1p[p];
        }
        h0[i * 35 + j] = a0; h1[i * 35 + j] = a1;
    }
}

// K5: compute y on the fly, per-block BN partials to unique slots (NO global atomics).
// STp [slot][oc]-major so k_bnfin reads coalesce.
__launch_bounds__(256)
__global__ void k_cs(const float* __restrict__ gmap, const float* __restrict__ U,
                     float* __restrict__ STp) {
    int tile = blockIdx.x, ocg = blockIdx.y, b = blockIdx.z;
    int ty0 = (tile / 6) * 32, tx0 = (tile % 6) * 32;
    __shared__ float h0[34 * 35], h1[34 * 35];
    stage_g(gmap, b, ty0, tx0, h0, h1);
    __syncthreads();

    int w = __builtin_amdgcn_readfirstlane(threadIdx.x >> 6);
    int lane = threadIdx.x & 63;
    int oc0 = ocg * 8 + w * 2;
    float u0[2][9], u1[2][9];
    #pragma unroll
    for (int j = 0; j < 2; j++) {
        const float* up = U + ((b * C + oc0 + j) * 2) * 9;
        #pragma unroll
        for (int t = 0; t < 9; t++) { u0[j][t] = up[t]; u1[j][t] = up[9 + t]; }
    }
    float s1[2] = {0.f, 0.f}, s2[2] = {0.f, 0.f};
    for (int it = 0; it < 4; it++) {
        int row = it * 8 + (lane >> 3);
        int c0 = (lane & 7) * 4;
        float g0v[3][6], g1v[3][6];
        #pragma unroll
        for (int dy = 0; dy < 3; dy++)
            #pragma unroll
            for (int dx = 0; dx < 6; dx++) {
                g0v[dy][dx] = h0[(row + dy) * 35 + c0 + dx];
                g1v[dy][dx] = h1[(row + dy) * 35 + c0 + dx];
            }
        #pragma unroll
        for (int j = 0; j < 2; j++)
            #pragma unroll
            for (int px = 0; px < 4; px++) {
                float y = 0.f;
                #pragma unroll
                for (int ky = 0; ky < 3; ky++)
                    #pragma unroll
                    for (int kx = 0; kx < 3; kx++) {
                        y += u0[j][ky * 3 + kx] * g0v[ky][px + kx];
                        y += u1[j][ky * 3 + kx] * g1v[ky][px + kx];
                    }
                s1[j] += y; s2[j] += y * y;
            }
    }
    #pragma unroll
    for (int j = 0; j < 2; j++) {
        float a = s1[j], q = s2[j];
        for (int off = 32; off > 0; off >>= 1) { a += __shfl_down(a, off); q += __shfl_down(q, off); }
        if (lane == 0) {
            int slot = b * 36 + tile;
            STp[slot * 64 + (oc0 + j)] = a;
            STp[288 * 64 + slot * 64 + (oc0 + j)] = q;
        }
    }
}

// K6: finalize BN scale/shift; STp [slot][oc]-major -> coalesced reads (fp64 accumulate)
__global__ void k_bnfin(const float* __restrict__ STp, const float* __restrict__ gamma,
                        const float* __restrict__ beta, float* __restrict__ scale,
                        float* __restrict__ shift) {
    int oc = threadIdx.x;
    double s = 0.0, s2 = 0.0;
    for (int k = 0; k < 288; k++) {
        s  += (double)STp[k * 64 + oc];
        s2 += (double)STp[288 * 64 + k * 64 + oc];
    }
    double n = (double)(B * P);
    double mean = s / n;
    double var = s2 / n - mean * mean;
    float sc = gamma[oc] * rsqrtf((float)var + 1e-5f);
    scale[oc] = sc;
    shift[oc] = beta[oc] - (float)mean * sc;
}

// K7: recompute y, out = x + relu(y*scale+shift)
__launch_bounds__(256)
__global__ void k_fin2(const float* __restrict__ gmap, const float* __restrict__ U,
                       const float* __restrict__ x,
                       const float* __restrict__ scale, const float* __restrict__ shift,
                       float* __restrict__ out) {
    int tile = blockIdx.x, ocg = blockIdx.y, b = blockIdx.z;
    int ty0 = (tile / 6) * 32, tx0 = (tile % 6) * 32;
    __shared__ float h0[34 * 35], h1[34 * 35];
    stage_g(gmap, b, ty0, tx0, h0, h1);
    __syncthreads();

    int w = __builtin_amdgcn_readfirstlane(threadIdx.x >> 6);
    int lane = threadIdx.x & 63;
    int oc0 = ocg * 8 + w * 2;
    float u0[2][9], u1[2][9], sc[2], sh[2];
    #pragma unroll
    for (int j = 0; j < 2; j++) {
        const float* up = U + ((b * C + oc0 + j) * 2) * 9;
        #pragma unroll
        for (int t = 0; t < 9; t++) { u0[j][t] = up[t]; u1[j][t] = up[9 + t]; }
        sc[j] = scale[oc0 + j]; sh[j] = shift[oc0 + j];
    }
    for (int it = 0; it < 4; it++) {
        int row = it * 8 + (lane >> 3);
        int c0 = (lane & 7) * 4;
        float g0v[3][6], g1v[3][6];
        #pragma unroll
        for (int dy = 0; dy < 3; dy++)
            #pragma unroll
            for (int dx = 0; dx < 6; dx++) {
                g0v[dy][dx] = h0[(row + dy) * 35 + c0 + dx];
                g1v[dy][dx] = h1[(row + dy) * 35 + c0 + dx];
            }
        #pragma unroll
        for (int j = 0; j < 2; j++) {
            float y4[4];
            #pragma unroll
            for (int px = 0; px < 4; px++) {
                float y = 0.f;
                #pragma unroll
                for (int ky = 0; ky < 3; ky++)
                    #pragma unroll
                    for (int kx = 0; kx < 3; kx++) {
                        y += u0[j][ky * 3 + kx] * g0v[ky][px + kx];
                        y += u1[j][ky * 3 + kx] * g1v[ky][px + kx];
                    }
                y4[px] = y;
            }
            int ga = (b * C + oc0 + j) * P + (ty0 + row) * WWD + tx0 + c0;
            float4 xv = *(const float4*)(x + ga);
            float4 ov;
            ov.x = fmaxf(y4[0] * sc[j] + sh[j], 0.f) + xv.x;
            ov.y = fmaxf(y4[1] * sc[j] + sh[j], 0.f) + xv.y;
            ov.z = fmaxf(y4[2] * sc[j] + sh[j], 0.f) + xv.z;
            ov.w = fmaxf(y4[3] * sc[j] + sh[j], 0.f) + xv.w;
            *(float4*)(out + ga) = ov;
        }
    }
}

extern "C" void kernel_launch(void* const* d_in, const int* in_sizes, int n_in,
                              void* d_out, int out_size, void* d_ws, size_t ws_size,
                              hipStream_t stream) {
    const float* x     = (const float*)d_in[0];
    const float* cs    = (const float*)d_in[1];
    const float* Wc    = (const float*)d_in[2];
    const float* Wxs   = (const float*)d_in[3];
    const float* Wcsp  = (const float*)d_in[4];
    const float* Wcval = (const float*)d_in[5];
    const float* Wattn = (const float*)d_in[6];
    const float* Wcomb = (const float*)d_in[7];
    const float* Wsing = (const float*)d_in[8];
    const float* gamma = (const float*)d_in[9];
    const float* beta  = (const float*)d_in[10];
    float* ws  = (float*)d_ws;
    float* out = (float*)d_out;

    float* spp   = ws + OFF_SPACE;
    float* Wt    = ws + OFF_WT;      // overlays spp (dead after k_R2)
    float* gmap  = ws + OFF_GM;      // overlays spp (dead after k_R2)
    float* Spart = ws + OFF_SPART;
    float* R     = ws + OFF_R;
    float* tok2  = ws + OFF_TOK2;
    float* U     = ws + OFF_U;
    float* STp   = ws + OFF_STP;
    float* scale = ws + OFF_SCALE;
    float* shift = ws + OFF_SHIFT;

    // zero padded-space halos + R accumulator + tok2 accumulator (contiguous range)
    hipMemsetAsync(ws, 0, (size_t)(OFF_TOK2 + 1024) * sizeof(float), stream);

    k_space<<<dim3(144, 16), 256, 0, stream>>>(cs, Wc, spp, Spart);
    k_R2   <<<dim3(8, 32, 8), 256, 0, stream>>>(x, spp, R);
    k_wt   <<<dim3(576, 8), 64, 0, stream>>>(Wxs, Wt);           // spp dead from here
    k_g    <<<dim3(144, 16), 256, 0, stream>>>(cs, Wcval, Wattn, Wcomb, gmap);
    k_tok2 <<<dim3(16, 8), 64, 0, stream>>>(Wt, Wcsp, R, Spart, tok2);
    k_U    <<<dim3(8, 2), 64, 0, stream>>>(Wsing, tok2, U);
    k_cs   <<<dim3(36, 8, 8), 256, 0, stream>>>(gmap, U, STp);
    k_bnfin<<<1, 64, 0, stream>>>(STp, gamma, beta, scale, shift);
    k_fin2 <<<dim3(36, 8, 8), 256, 0, stream>>>(gmap, U, x, scale, shift, out);
}

// Round 7
// 887.122 us; speedup vs baseline: 4.3264x; 4.3264x over previous
//
#include <hip/hip_runtime.h>
#include <math.h>

// Problem constants (fixed by reference setup_inputs)
#define B   8
#define C   64
#define HH  192
#define WWD 192
#define P   (HH*WWD)     // 36864
#define NC  2
#define NS  8
#define PP  (194*194)    // padded space map (1-px zero halo), 37636

// Workspace layout (float offsets)
#define OFF_SPACE 0                    // 128 maps * PP = 4817408 (zero-padded)
// Wt and gmap REUSE the spp region (dead after k_R2): k_wt/k_g run after k_R2.
#define OFF_WT    0                    // 8*576*64 = 294912 transposed Wxs
#define OFF_GM    294912               // 8*2*P = 589824 combined attention maps
#define OFF_SPART 4817408              // 128*144 per-block S partials
#define OFF_R     4835840              // 8*16*64*9 = 73728 correlations (zeroed; k_R2 atomically accumulates)
#define OFF_TOK2  4909568              // 8*2*64 = 1024 (atomic accumulated, needs zero)
#define OFF_U     4910592              // 8*64*2*9 = 9216 collapsed conv weights
#define OFF_STP   4919808              // 2*64*288 BN partial sums ([slot][oc] major)
#define OFF_SCALE 4956672              // 64
#define OFF_SHIFT 4956736              // 64
#define WS_FLOATS 4956800              // ~19.8 MB total

__device__ __forceinline__ float sigm(float x) { return 1.0f / (1.0f + expf(-x)); }

// K1: space maps (sigmoid + 1->7 ch 3x3 conv + sigmoid) into zero-padded layout,
// plus per-(map,ch) per-block partial sums (NO global atomics).
__global__ void k_space(const float* __restrict__ cs, const float* __restrict__ Wc,
                        float* __restrict__ spp, float* __restrict__ Spart) {
    int m = blockIdx.y;                       // m = b*2 + c
    int bx = blockIdx.x;
    int p = bx * 256 + threadIdx.x;           // 144*256 == P exactly
    int h = p / WWD, w = p - (p / WWD) * WWD;
    float cp[9];
    #pragma unroll
    for (int ky = 0; ky < 3; ky++)
        #pragma unroll
        for (int kx = 0; kx < 3; kx++) {
            int hh = h + ky - 1, ww = w + kx - 1;
            float v = 0.f;  // zero-pad AFTER sigmoid (conv pads class_prob with 0)
            if ((unsigned)hh < HH && (unsigned)ww < WWD)
                v = sigm(cs[m * P + hh * WWD + ww]);
            cp[ky * 3 + kx] = v;
        }
    float ch[8];
    ch[0] = cp[4];
    #pragma unroll
    for (int j = 0; j < 7; j++) {
        float a = 0.f;
        #pragma unroll
        for (int k = 0; k < 9; k++) a += Wc[j * 9 + k] * cp[k];
        ch[j + 1] = sigm(a);
    }
    #pragma unroll
    for (int q = 0; q < 8; q++)
        spp[(m * 8 + q) * PP + (h + 1) * 194 + (w + 1)] = ch[q];
    // per-wave shfl reduce -> LDS -> per-block partial (no atomics)
    __shared__ float red[4][8];
    int lane = threadIdx.x & 63, wave = threadIdx.x >> 6;
    #pragma unroll
    for (int q = 0; q < 8; q++) {
        float v = ch[q];
        for (int off = 32; off > 0; off >>= 1) v += __shfl_down(v, off);
        if (lane == 0) red[wave][q] = v;
    }
    __syncthreads();
    if (threadIdx.x < 8) {
        int q = threadIdx.x;
        Spart[(m * 8 + q) * 144 + bx] = red[0][q] + red[1][q] + red[2][q] + red[3][q];
    }
}

// K2: correlation, RESTRUCTURED (R6 post-mortem): the 43% VALUBusy plateau is
// per-CU L2 delivery bandwidth on x re-reads (each x byte read 16x, once per map).
// New wave layout: lane = scs(2b)*16 + pl(4b) -> 16 px-lanes x 4 maps per wave.
// x is loaded ONCE per wave-iter (2 float4 instrs; lane supplies (ch-sub, px))
// and broadcast to the 4 map-groups via __shfl (DS pipe, cheap). x bytes per
// wave-iter: 8KB -> 2KB. Each lane keeps the proven acc[8][9]=72-reg core for
// ITS map; live set ~115 regs fits the (256,4) 128-reg band -- no extra
// load buffers, no barriers (waves independent), no LDS staging.
// Grid: (ksplit 16) x (b*8+ig 64), 4 waves/block cover all 16 maps.
// Partials: width-16 shfl reduce over px-lanes, atomicAdd into R (pre-zeroed).
__launch_bounds__(256, 4)
__global__ void k_R2(const float* __restrict__ x, const float* __restrict__ spp,
                     float* __restrict__ R) {
    int ks = blockIdx.x;          // 0..15 : K-split chunk (2304 px = 12 rows)
    int bz = blockIdx.y;          // 0..63 : b*8 + ig
    int b = bz >> 3, ig = bz & 7;
    int lane = threadIdx.x & 63;
    int wv   = threadIdx.x >> 6;  // 0..3 : sc quad
    int pl   = lane & 15;         // px-lane
    int scs  = lane >> 4;         // map within quad
    int sc   = wv * 4 + scs;      // 0..15 = s*2+c
    int s = sc >> 1, c = sc & 1;
    const float* xb = x + (b * C + ig * 8) * P;
    const float* sp = spp + ((b * NC + c) * NS + s) * PP;

    float acc[8][9];
    #pragma unroll
    for (int i = 0; i < 8; i++)
        #pragma unroll
        for (int t = 0; t < 9; t++) acc[i][t] = 0.f;

    const int chunk = ks * 2304;
    for (int it = 0; it < 36; it++) {
        int p0 = chunk + it * 64 + pl * 4;
        // x loads: THIS lane supplies ch-sub {scs, scs+4} at px pl*4 (2KB/wave-iter)
        float4 xl0 = *(const float4*)(xb + scs * P + p0);
        float4 xl1 = *(const float4*)(xb + (scs + 4) * P + p0);
        int h = p0 / WWD, w0 = p0 - (p0 / WWD) * WWD;
        float g[3][6];
        #pragma unroll
        for (int ty = 0; ty < 3; ty++) {
            const float* rp = sp + (h + 2 - ty) * 194 + w0;
            float4 ga; float2 gb;
            __builtin_memcpy(&ga, rp, 16);
            __builtin_memcpy(&gb, rp + 4, 8);
            g[ty][0] = ga.x; g[ty][1] = ga.y; g[ty][2] = ga.z;
            g[ty][3] = ga.w; g[ty][4] = gb.x; g[ty][5] = gb.y;
        }
        #pragma unroll
        for (int ch = 0; ch < 8; ch++) {
            int src = ((ch & 3) << 4) | pl;     // lane holding (ch, my px)
            float4 q;
            if (ch < 4) q = xl0; else q = xl1;  // compile-time select (unrolled)
            float4 xv;
            xv.x = __shfl(q.x, src); xv.y = __shfl(q.y, src);
            xv.z = __shfl(q.z, src); xv.w = __shfl(q.w, src);
            #pragma unroll
            for (int ty = 0; ty < 3; ty++)
                #pragma unroll
                for (int tx = 0; tx < 3; tx++) {
                    float a = acc[ch][ty * 3 + tx];
                    a += xv.x * g[ty][2 - tx]; a += xv.y * g[ty][3 - tx];
                    a += xv.z * g[ty][4 - tx]; a += xv.w * g[ty][5 - tx];
                    acc[ch][ty * 3 + tx] = a;
                }
        }
    }

    // reduce over the 16 px-lanes within each map group, then atomic into R
    #pragma unroll
    for (int ch = 0; ch < 8; ch++)
        #pragma unroll
        for (int t = 0; t < 9; t++) {
            float v = acc[ch][t];
            v += __shfl_down(v, 8, 16);
            v += __shfl_down(v, 4, 16);
            v += __shfl_down(v, 2, 16);
            v += __shfl_down(v, 1, 16);
            if (pl == 0)
                atomicAdd(&R[((b * 16 + sc) * 64 + (ig * 8 + ch)) * 9 + t], v);
        }
}

// K2b: transpose Wxs into Wt[s][t][d] so k_tok2's weight reads are lane-coalesced.
// Runs AFTER k_R2 (Wt lives in the dead spp region). 1.2 MB, trivial.
__global__ void k_wt(const float* __restrict__ Wxs, float* __restrict__ Wt) {
    int t = blockIdx.x;   // 0..575
    int s = blockIdx.y;   // 0..7
    int d = threadIdx.x;  // 0..63
    Wt[(s * 576 + t) * 64 + d] = Wxs[(s * 64 + d) * 576 + t];
}

// K2c: combined attention map gmap[b][cl][p] = sum_s Wcomb[s]*Wcval[s]*sigm(sigm(cs)*Wattn[s])
// Computed ONCE per pixel (was recomputed 8x per ocg in k_cs AND k_fin2).
__global__ void k_g(const float* __restrict__ cs, const float* __restrict__ Wcval,
                    const float* __restrict__ Wattn, const float* __restrict__ Wcomb,
                    float* __restrict__ gmap) {
    int m = blockIdx.y;                       // b*2 + cl
    int p = blockIdx.x * 256 + threadIdx.x;   // 144*256 == P
    float wa[8], wt[8];
    #pragma unroll
    for (int s = 0; s < 8; s++) { wa[s] = Wcomb[s] * Wcval[s]; wt[s] = Wattn[s]; }
    float cp = sigm(cs[m * P + p]);
    float a = 0.f;
    #pragma unroll
    for (int s = 0; s < 8; s++) a += wa[s] * sigm(cp * wt[s]);
    gmap[m * P + p] = a;
}

// K3: tok2[b,c,d] = sum_s Wcs[s]/S[b,c,s] * sum_{t} Wt[s][t][d] * R[b,s,c,t]
// Wt transposed -> coalesced weight loads; R row is a broadcast (L1-served).
__global__ void k_tok2(const float* __restrict__ Wt, const float* __restrict__ Wcs,
                       const float* __restrict__ R, const float* __restrict__ Spart,
                       float* __restrict__ tok2) {
    int bc = blockIdx.x, s = blockIdx.y;
    int d = threadIdx.x;
    const float* spp = Spart + (bc * 8 + s) * 144;
    float sv = 0.f;
    for (int k = d; k < 144; k += 64) sv += spp[k];
    #pragma unroll
    for (int msk = 32; msk >= 1; msk >>= 1) sv += __shfl_xor(sv, msk);

    const float* Rp = R + ((bc & 1) + ((bc >> 1) * 16 + s * 2)) * 576;
    const float* Wp = Wt + s * 576 * 64 + d;
    float a = 0.f;
    #pragma unroll 4
    for (int t = 0; t < 576; t++) a += Wp[t * 64] * Rp[t];
    float val = a * Wcs[s] / sv;
    atomicAdd(&tok2[bc * C + d], val);   // 8K atomics over 1024 addrs — negligible
}

// K4: collapse conv weights against tok2:  U[b][oc][m][t] = sum_ci Ws[oc,ci,t] * tok2[b,m,ci]
__global__ void k_U(const float* __restrict__ Ws, const float* __restrict__ tok2,
                    float* __restrict__ U) {
    int b = blockIdx.x, m = blockIdx.y, oc = threadIdx.x;
    const float* tp = tok2 + (b * NC + m) * C;
    float u[9];
    #pragma unroll
    for (int t = 0; t < 9; t++) u[t] = 0.f;
    for (int ci = 0; ci < C; ci++) {
        float tv = tp[ci];
        const float* wp = Ws + (oc * C + ci) * 9;
        #pragma unroll
        for (int t = 0; t < 9; t++) u[t] += wp[t] * tv;
    }
    float* up = U + ((b * C + oc) * 2 + m) * 9;
    #pragma unroll
    for (int t = 0; t < 9; t++) up[t] = u[t];
}

// Shared staging: g0/g1 34x34 halo tiles from precomputed gmap (pure coalesced copy).
__device__ __forceinline__ void stage_g(const float* __restrict__ gmap, int b, int ty0, int tx0,
                                        float* h0, float* h1) {
    const float* g0p = gmap + (b * NC + 0) * P;
    const float* g1p = gmap + (b * NC + 1) * P;
    for (int idx = threadIdx.x; idx < 34 * 34; idx += 256) {
        int i = idx / 34, j = idx - (idx / 34) * 34;
        int gy = ty0 - 1 + i, gx = tx0 - 1 + j;
        float a0 = 0.f, a1 = 0.f;
        if ((unsigned)gy < HH && (unsigned)gx < WWD) {
            int p = gy * WWD + gx;
            a0 = g0p[p]; a1 = g1p[p];
        }
        h0[i * 35 + j] = a0; h1[i * 35 + j] = a1;
    }
}

// K5: compute y on the fly, per-block BN partials to unique slots (NO global atomics).
// STp [slot][oc]-major so k_bnfin reads coalesce.
__launch_bounds__(256)
__global__ void k_cs(const float* __restrict__ gmap, const float* __restrict__ U,
                     float* __restrict__ STp) {
    int tile = blockIdx.x, ocg = blockIdx.y, b = blockIdx.z;
    int ty0 = (tile / 6) * 32, tx0 = (tile % 6) * 32;
    __shared__ float h0[34 * 35], h1[34 * 35];
    stage_g(gmap, b, ty0, tx0, h0, h1);
    __syncthreads();

    int w = __builtin_amdgcn_readfirstlane(threadIdx.x >> 6);
    int lane = threadIdx.x & 63;
    int oc0 = ocg * 8 + w * 2;
    float u0[2][9], u1[2][9];
    #pragma unroll
    for (int j = 0; j < 2; j++) {
        const float* up = U + ((b * C + oc0 + j) * 2) * 9;
        #pragma unroll
        for (int t = 0; t < 9; t++) { u0[j][t] = up[t]; u1[j][t] = up[9 + t]; }
    }
    float s1[2] = {0.f, 0.f}, s2[2] = {0.f, 0.f};
    for (int it = 0; it < 4; it++) {
        int row = it * 8 + (lane >> 3);
        int c0 = (lane & 7) * 4;
        float g0v[3][6], g1v[3][6];
        #pragma unroll
        for (int dy = 0; dy < 3; dy++)
            #pragma unroll
            for (int dx = 0; dx < 6; dx++) {
                g0v[dy][dx] = h0[(row + dy) * 35 + c0 + dx];
                g1v[dy][dx] = h1[(row + dy) * 35 + c0 + dx];
            }
        #pragma unroll
        for (int j = 0; j < 2; j++)
            #pragma unroll
            for (int px = 0; px < 4; px++) {
                float y = 0.f;
                #pragma unroll
                for (int ky = 0; ky < 3; ky++)
                    #pragma unroll
                    for (int kx = 0; kx < 3; kx++) {
                        y += u0[j][ky * 3 + kx] * g0v[ky][px + kx];
                        y += u1[j][ky * 3 + kx] * g1v[ky][px + kx];
                    }
                s1[j] += y; s2[j] += y * y;
            }
    }
    #pragma unroll
    for (int j = 0; j < 2; j++) {
        float a = s1[j], q = s2[j];
        for (int off = 32; off > 0; off >>= 1) { a += __shfl_down(a, off); q += __shfl_down(q, off); }
        if (lane == 0) {
            int slot = b * 36 + tile;
            STp[slot * 64 + (oc0 + j)] = a;
            STp[288 * 64 + slot * 64 + (oc0 + j)] = q;
        }
    }
}

// K6: finalize BN scale/shift; STp [slot][oc]-major -> coalesced reads (fp64 accumulate)
__global__ void k_bnfin(const float* __restrict__ STp, const float* __restrict__ gamma,
                        const float* __restrict__ beta, float* __restrict__ scale,
                        float* __restrict__ shift) {
    int oc = threadIdx.x;
    double s = 0.0, s2 = 0.0;
    for (int k = 0; k < 288; k++) {
        s  += (double)STp[k * 64 + oc];
        s2 += (double)STp[288 * 64 + k * 64 + oc];
    }
    double n = (double)(B * P);
    double mean = s / n;
    double var = s2 / n - mean * mean;
    float sc = gamma[oc] * rsqrtf((float)var + 1e-5f);
    scale[oc] = sc;
    shift[oc] = beta[oc] - (float)mean * sc;
}

// K7: recompute y, out = x + relu(y*scale+shift)
__launch_bounds__(256)
__global__ void k_fin2(const float* __restrict__ gmap, const float* __restrict__ U,
                       const float* __restrict__ x,
                       const float* __restrict__ scale, const float* __restrict__ shift,
                       float* __restrict__ out) {
    int tile = blockIdx.x, ocg = blockIdx.y, b = blockIdx.z;
    int ty0 = (tile / 6) * 32, tx0 = (tile % 6) * 32;
    __shared__ float h0[34 * 35], h1[34 * 35];
    stage_g(gmap, b, ty0, tx0, h0, h1);
    __syncthreads();

    int w = __builtin_amdgcn_readfirstlane(threadIdx.x >> 6);
    int lane = threadIdx.x & 63;
    int oc0 = ocg * 8 + w * 2;
    float u0[2][9], u1[2][9], sc[2], sh[2];
    #pragma unroll
    for (int j = 0; j < 2; j++) {
        const float* up = U + ((b * C + oc0 + j) * 2) * 9;
        #pragma unroll
        for (int t = 0; t < 9; t++) { u0[j][t] = up[t]; u1[j][t] = up[9 + t]; }
        sc[j] = scale[oc0 + j]; sh[j] = shift[oc0 + j];
    }
    for (int it = 0; it < 4; it++) {
        int row = it * 8 + (lane >> 3);
        int c0 = (lane & 7) * 4;
        float g0v[3][6], g1v[3][6];
        #pragma unroll
        for (int dy = 0; dy < 3; dy++)
            #pragma unroll
            for (int dx = 0; dx < 6; dx++) {
                g0v[dy][dx] = h0[(row + dy) * 35 + c0 + dx];
                g1v[dy][dx] = h1[(row + dy) * 35 + c0 + dx];
            }
        #pragma unroll
        for (int j = 0; j < 2; j++) {
            float y4[4];
            #pragma unroll
            for (int px = 0; px < 4; px++) {
                float y = 0.f;
                #pragma unroll
                for (int ky = 0; ky < 3; ky++)
                    #pragma unroll
                    for (int kx = 0; kx < 3; kx++) {
                        y += u0[j][ky * 3 + kx] * g0v[ky][px + kx];
                        y += u1[j][ky * 3 + kx] * g1v[ky][px + kx];
                    }
                y4[px] = y;
            }
            int ga = (b * C + oc0 + j) * P + (ty0 + row) * WWD + tx0 + c0;
            float4 xv = *(const float4*)(x + ga);
            float4 ov;
            ov.x = fmaxf(y4[0] * sc[j] + sh[j], 0.f) + xv.x;
            ov.y = fmaxf(y4[1] * sc[j] + sh[j], 0.f) + xv.y;
            ov.z = fmaxf(y4[2] * sc[j] + sh[j], 0.f) + xv.z;
            ov.w = fmaxf(y4[3] * sc[j] + sh[j], 0.f) + xv.w;
            *(float4*)(out + ga) = ov;
        }
    }
}

extern "C" void kernel_launch(void* const* d_in, const int* in_sizes, int n_in,
                              void* d_out, int out_size, void* d_ws, size_t ws_size,
                              hipStream_t stream) {
    const float* x     = (const float*)d_in[0];
    const float* cs    = (const float*)d_in[1];
    const float* Wc    = (const float*)d_in[2];
    const float* Wxs   = (const float*)d_in[3];
    const float* Wcsp  = (const float*)d_in[4];
    const float* Wcval = (const float*)d_in[5];
    const float* Wattn = (const float*)d_in[6];
    const float* Wcomb = (const float*)d_in[7];
    const float* Wsing = (const float*)d_in[8];
    const float* gamma = (const float*)d_in[9];
    const float* beta  = (const float*)d_in[10];
    float* ws  = (float*)d_ws;
    float* out = (float*)d_out;

    float* spp   = ws + OFF_SPACE;
    float* Wt    = ws + OFF_WT;      // overlays spp (dead after k_R2)
    float* gmap  = ws + OFF_GM;      // overlays spp (dead after k_R2)
    float* Spart = ws + OFF_SPART;
    float* R     = ws + OFF_R;
    float* tok2  = ws + OFF_TOK2;
    float* U     = ws + OFF_U;
    float* STp   = ws + OFF_STP;
    float* scale = ws + OFF_SCALE;
    float* shift = ws + OFF_SHIFT;

    // zero padded-space halos + R accumulator + tok2 accumulator (contiguous range)
    hipMemsetAsync(ws, 0, (size_t)(OFF_TOK2 + 1024) * sizeof(float), stream);

    k_space<<<dim3(144, 16), 256, 0, stream>>>(cs, Wc, spp, Spart);
    k_R2   <<<dim3(16, 64), 256, 0, stream>>>(x, spp, R);
    k_wt   <<<dim3(576, 8), 64, 0, stream>>>(Wxs, Wt);           // spp dead from here
    k_g    <<<dim3(144, 16), 256, 0, stream>>>(cs, Wcval, Wattn, Wcomb, gmap);
    k_tok2 <<<dim3(16, 8), 64, 0, stream>>>(Wt, Wcsp, R, Spart, tok2);
    k_U    <<<dim3(8, 2), 64, 0, stream>>>(Wsing, tok2, U);
    k_cs   <<<dim3(36, 8, 8), 256, 0, stream>>>(gmap, U, STp);
    k_bnfin<<<1, 64, 0, stream>>>(STp, gamma, beta, scale, shift);
    k_fin2 <<<dim3(36, 8, 8), 256, 0, stream>>>(gmap, U, x, scale, shift, out);
}

// Round 8
// 578.610 us; speedup vs baseline: 6.6332x; 1.5332x over previous
//
#include <hip/hip_runtime.h>
#include <math.h>

// Problem constants (fixed by reference setup_inputs)
#define B   8
#define C   64
#define HH  192
#define WWD 192
#define P   (HH*WWD)     // 36864
#define NC  2
#define NS  8
#define PP  (194*194)    // padded space map (1-px zero halo), 37636

// Workspace layout (float offsets)
#define OFF_SPACE 0                    // 128 maps * PP = 4817408 (zero-padded)
// Wt and gmap REUSE the spp region (dead after k_R2): k_wt/k_g run after k_R2.
#define OFF_WT    0                    // 8*576*64 = 294912 transposed Wxs
#define OFF_GM    294912               // 8*2*P = 589824 combined attention maps
#define OFF_SPART 4817408              // 128*144 per-block S partials
#define OFF_R     4835840              // 8*16*64*9 = 73728 correlations (zeroed; k_R2 atomically accumulates)
#define OFF_TOK2  4909568              // 8*2*64 = 1024 (atomic accumulated, needs zero)
#define OFF_U     4910592              // 8*64*2*9 = 9216 collapsed conv weights
#define OFF_STP   4919808              // 2*64*288 BN partial sums ([slot][oc] major)
#define OFF_SCALE 4956672              // 64
#define OFF_SHIFT 4956736              // 64
#define WS_FLOATS 4956800              // ~19.8 MB total

__device__ __forceinline__ float sigm(float x) { return 1.0f / (1.0f + expf(-x)); }

// K1: space maps (sigmoid + 1->7 ch 3x3 conv + sigmoid) into zero-padded layout,
// plus per-(map,ch) per-block partial sums (NO global atomics).
__global__ void k_space(const float* __restrict__ cs, const float* __restrict__ Wc,
                        float* __restrict__ spp, float* __restrict__ Spart) {
    int m = blockIdx.y;                       // m = b*2 + c
    int bx = blockIdx.x;
    int p = bx * 256 + threadIdx.x;           // 144*256 == P exactly
    int h = p / WWD, w = p - (p / WWD) * WWD;
    float cp[9];
    #pragma unroll
    for (int ky = 0; ky < 3; ky++)
        #pragma unroll
        for (int kx = 0; kx < 3; kx++) {
            int hh = h + ky - 1, ww = w + kx - 1;
            float v = 0.f;  // zero-pad AFTER sigmoid (conv pads class_prob with 0)
            if ((unsigned)hh < HH && (unsigned)ww < WWD)
                v = sigm(cs[m * P + hh * WWD + ww]);
            cp[ky * 3 + kx] = v;
        }
    float ch[8];
    ch[0] = cp[4];
    #pragma unroll
    for (int j = 0; j < 7; j++) {
        float a = 0.f;
        #pragma unroll
        for (int k = 0; k < 9; k++) a += Wc[j * 9 + k] * cp[k];
        ch[j + 1] = sigm(a);
    }
    #pragma unroll
    for (int q = 0; q < 8; q++)
        spp[(m * 8 + q) * PP + (h + 1) * 194 + (w + 1)] = ch[q];
    // per-wave shfl reduce -> LDS -> per-block partial (no atomics)
    __shared__ float red[4][8];
    int lane = threadIdx.x & 63, wave = threadIdx.x >> 6;
    #pragma unroll
    for (int q = 0; q < 8; q++) {
        float v = ch[q];
        for (int off = 32; off > 0; off >>= 1) v += __shfl_down(v, off);
        if (lane == 0) red[wave][q] = v;
    }
    __syncthreads();
    if (threadIdx.x < 8) {
        int q = threadIdx.x;
        Spart[(m * 8 + q) * 144 + bx] = red[0][q] + red[1][q] + red[2][q] + red[3][q];
    }
}

// K2: correlation with LDS-shared x (R7 post-mortem: keep the per-lane dataflow
// IDENTICAL to the proven 84-reg core; cut x traffic in LDS, not registers).
// Block = 256 threads = 4 waves; block owns (map-quad mq, b, ig, k-chunk).
// Per 1024-px tile: cooperatively stage x[8ch][1024px] (32KB) to LDS once, then
// EACH WAVE processes its OWN map over the full tile (4 sub-iters x 256 px),
// reading x via conflict-free lane-contiguous ds_read_b128, one float4 at a
// time (immediately consumed -> no extra live registers). x global traffic
// 1.2GB -> 300MB (4 maps share each staged byte); x re-reads served by LDS.
// Live set per lane: acc 72 + g 18 + xv 4 + addr ~ 100 regs. Grid 4x64x4 ->
// 4-5 blocks/CU residency hides the staging latency (no prefetch registers).
__launch_bounds__(256, 3)
__global__ void k_R2(const float* __restrict__ x, const float* __restrict__ spp,
                     float* __restrict__ R) {
    int mq = blockIdx.x;          // 0..3 : map quad
    int bz = blockIdx.y;          // 0..63 : b*8 + ig
    int ks = blockIdx.z;          // 0..3 : K-split chunk (9 tiles each)
    int b = bz >> 3, ig = bz & 7;
    int tid = threadIdx.x;
    int wv = tid >> 6, lane = tid & 63;
    int sc = mq * 4 + wv;         // this wave's map, 0..15 = s*2+c
    int s = sc >> 1, c = sc & 1;
    const float* xb = x + (b * C + ig * 8) * P;
    const float* sp = spp + ((b * NC + c) * NS + s) * PP;

    __shared__ float xt[8][1024];  // 32 KB staged x tile

    float acc[8][9];
    #pragma unroll
    for (int i = 0; i < 8; i++)
        #pragma unroll
        for (int t = 0; t < 9; t++) acc[i][t] = 0.f;

    for (int t9 = 0; t9 < 9; t9++) {
        int tile = (ks * 9 + t9) * 1024;
        // cooperative stage: thread tid owns px [tid*4, tid*4+4) for all 8 ch
        {
            int px = tid * 4;
            #pragma unroll
            for (int i = 0; i < 8; i++) {
                float4 v = *(const float4*)(xb + i * P + tile + px);
                *(float4*)(&xt[i][px]) = v;
            }
        }
        __syncthreads();
        for (int sub = 0; sub < 4; sub++) {
            int lpx = sub * 256 + lane * 4;
            int p0 = tile + lpx;
            int h = p0 / WWD, w0 = p0 - (p0 / WWD) * WWD;
            float g[3][6];
            #pragma unroll
            for (int ty = 0; ty < 3; ty++) {
                const float* rp = sp + (h + 2 - ty) * 194 + w0;
                float4 ga; float2 gb;
                __builtin_memcpy(&ga, rp, 16);
                __builtin_memcpy(&gb, rp + 4, 8);
                g[ty][0] = ga.x; g[ty][1] = ga.y; g[ty][2] = ga.z;
                g[ty][3] = ga.w; g[ty][4] = gb.x; g[ty][5] = gb.y;
            }
            #pragma unroll
            for (int i = 0; i < 8; i++) {
                float4 xv = *(const float4*)(&xt[i][lpx]);
                #pragma unroll
                for (int ty = 0; ty < 3; ty++)
                    #pragma unroll
                    for (int tx = 0; tx < 3; tx++) {
                        float a = acc[i][ty * 3 + tx];
                        a += xv.x * g[ty][2 - tx]; a += xv.y * g[ty][3 - tx];
                        a += xv.z * g[ty][4 - tx]; a += xv.w * g[ty][5 - tx];
                        acc[i][ty * 3 + tx] = a;
                    }
            }
        }
        __syncthreads();
    }

    // per-wave shfl reduce (each wave owns its map) -> atomicAdd into R
    #pragma unroll
    for (int i = 0; i < 8; i++)
        #pragma unroll
        for (int t = 0; t < 9; t++) {
            float v = acc[i][t];
            for (int off = 32; off > 0; off >>= 1) v += __shfl_down(v, off);
            if (lane == 0)
                atomicAdd(&R[((b * 16 + sc) * 64 + (ig * 8 + i)) * 9 + t], v);
        }
}

// K2b: transpose Wxs into Wt[s][t][d] so k_tok2's weight reads are lane-coalesced.
// Runs AFTER k_R2 (Wt lives in the dead spp region). 1.2 MB, trivial.
__global__ void k_wt(const float* __restrict__ Wxs, float* __restrict__ Wt) {
    int t = blockIdx.x;   // 0..575
    int s = blockIdx.y;   // 0..7
    int d = threadIdx.x;  // 0..63
    Wt[(s * 576 + t) * 64 + d] = Wxs[(s * 64 + d) * 576 + t];
}

// K2c: combined attention map gmap[b][cl][p] = sum_s Wcomb[s]*Wcval[s]*sigm(sigm(cs)*Wattn[s])
// Computed ONCE per pixel (was recomputed 8x per ocg in k_cs AND k_fin2).
__global__ void k_g(const float* __restrict__ cs, const float* __restrict__ Wcval,
                    const float* __restrict__ Wattn, const float* __restrict__ Wcomb,
                    float* __restrict__ gmap) {
    int m = blockIdx.y;                       // b*2 + cl
    int p = blockIdx.x * 256 + threadIdx.x;   // 144*256 == P
    float wa[8], wt[8];
    #pragma unroll
    for (int s = 0; s < 8; s++) { wa[s] = Wcomb[s] * Wcval[s]; wt[s] = Wattn[s]; }
    float cp = sigm(cs[m * P + p]);
    float a = 0.f;
    #pragma unroll
    for (int s = 0; s < 8; s++) a += wa[s] * sigm(cp * wt[s]);
    gmap[m * P + p] = a;
}

// K3: tok2[b,c,d] = sum_s Wcs[s]/S[b,c,s] * sum_{t} Wt[s][t][d] * R[b,s,c,t]
// Wt transposed -> coalesced weight loads; R row is a broadcast (L1-served).
__global__ void k_tok2(const float* __restrict__ Wt, const float* __restrict__ Wcs,
                       const float* __restrict__ R, const float* __restrict__ Spart,
                       float* __restrict__ tok2) {
    int bc = blockIdx.x, s = blockIdx.y;
    int d = threadIdx.x;
    const float* spp = Spart + (bc * 8 + s) * 144;
    float sv = 0.f;
    for (int k = d; k < 144; k += 64) sv += spp[k];
    #pragma unroll
    for (int msk = 32; msk >= 1; msk >>= 1) sv += __shfl_xor(sv, msk);

    const float* Rp = R + ((bc & 1) + ((bc >> 1) * 16 + s * 2)) * 576;
    const float* Wp = Wt + s * 576 * 64 + d;
    float a = 0.f;
    #pragma unroll 4
    for (int t = 0; t < 576; t++) a += Wp[t * 64] * Rp[t];
    float val = a * Wcs[s] / sv;
    atomicAdd(&tok2[bc * C + d], val);   // 8K atomics over 1024 addrs — negligible
}

// K4: collapse conv weights against tok2:  U[b][oc][m][t] = sum_ci Ws[oc,ci,t] * tok2[b,m,ci]
__global__ void k_U(const float* __restrict__ Ws, const float* __restrict__ tok2,
                    float* __restrict__ U) {
    int b = blockIdx.x, m = blockIdx.y, oc = threadIdx.x;
    const float* tp = tok2 + (b * NC + m) * C;
    float u[9];
    #pragma unroll
    for (int t = 0; t < 9; t++) u[t] = 0.f;
    for (int ci = 0; ci < C; ci++) {
        float tv = tp[ci];
        const float* wp = Ws + (oc * C + ci) * 9;
        #pragma unroll
        for (int t = 0; t < 9; t++) u[t] += wp[t] * tv;
    }
    float* up = U + ((b * C + oc) * 2 + m) * 9;
    #pragma unroll
    for (int t = 0; t < 9; t++) up[t] = u[t];
}

// Shared staging: g0/g1 34x34 halo tiles from precomputed gmap (pure coalesced copy).
__device__ __forceinline__ void stage_g(const float* __restrict__ gmap, int b, int ty0, int tx0,
                                        float* h0, float* h1) {
    const float* g0p = gmap + (b * NC + 0) * P;
    const float* g1p = gmap + (b * NC + 1) * P;
    for (int idx = threadIdx.x; idx < 34 * 34; idx += 256) {
        int i = idx / 34, j = idx - (idx / 34) * 34;
        int gy = ty0 - 1 + i, gx = tx0 - 1 + j;
        float a0 = 0.f, a1 = 0.f;
        if ((unsigned)gy < HH && (unsigned)gx < WWD) {
            int p = gy * WWD + gx;
            a0 = g0p[p]; a1 = g1p[p];
        }
        h0[i * 35 + j] = a0; h1[i * 35 + j] = a1;
    }
}

// K5: compute y on the fly, per-block BN partials to unique slots (NO global atomics).
// STp [slot][oc]-major so k_bnfin reads coalesce.
__launch_bounds__(256)
__global__ void k_cs(const float* __restrict__ gmap, const float* __restrict__ U,
                     float* __restrict__ STp) {
    int tile = blockIdx.x, ocg = blockIdx.y, b = blockIdx.z;
    int ty0 = (tile / 6) * 32, tx0 = (tile % 6) * 32;
    __shared__ float h0[34 * 35], h1[34 * 35];
    stage_g(gmap, b, ty0, tx0, h0, h1);
    __syncthreads();

    int w = __builtin_amdgcn_readfirstlane(threadIdx.x >> 6);
    int lane = threadIdx.x & 63;
    int oc0 = ocg * 8 + w * 2;
    float u0[2][9], u1[2][9];
    #pragma unroll
    for (int j = 0; j < 2; j++) {
        const float* up = U + ((b * C + oc0 + j) * 2) * 9;
        #pragma unroll
        for (int t = 0; t < 9; t++) { u0[j][t] = up[t]; u1[j][t] = up[9 + t]; }
    }
    float s1[2] = {0.f, 0.f}, s2[2] = {0.f, 0.f};
    for (int it = 0; it < 4; it++) {
        int row = it * 8 + (lane >> 3);
        int c0 = (lane & 7) * 4;
        float g0v[3][6], g1v[3][6];
        #pragma unroll
        for (int dy = 0; dy < 3; dy++)
            #pragma unroll
            for (int dx = 0; dx < 6; dx++) {
                g0v[dy][dx] = h0[(row + dy) * 35 + c0 + dx];
                g1v[dy][dx] = h1[(row + dy) * 35 + c0 + dx];
            }
        #pragma unroll
        for (int j = 0; j < 2; j++)
            #pragma unroll
            for (int px = 0; px < 4; px++) {
                float y = 0.f;
                #pragma unroll
                for (int ky = 0; ky < 3; ky++)
                    #pragma unroll
                    for (int kx = 0; kx < 3; kx++) {
                        y += u0[j][ky * 3 + kx] * g0v[ky][px + kx];
                        y += u1[j][ky * 3 + kx] * g1v[ky][px + kx];
                    }
                s1[j] += y; s2[j] += y * y;
            }
    }
    #pragma unroll
    for (int j = 0; j < 2; j++) {
        float a = s1[j], q = s2[j];
        for (int off = 32; off > 0; off >>= 1) { a += __shfl_down(a, off); q += __shfl_down(q, off); }
        if (lane == 0) {
            int slot = b * 36 + tile;
            STp[slot * 64 + (oc0 + j)] = a;
            STp[288 * 64 + slot * 64 + (oc0 + j)] = q;
        }
    }
}

// K6: finalize BN scale/shift; STp [slot][oc]-major -> coalesced reads (fp64 accumulate)
__global__ void k_bnfin(const float* __restrict__ STp, const float* __restrict__ gamma,
                        const float* __restrict__ beta, float* __restrict__ scale,
                        float* __restrict__ shift) {
    int oc = threadIdx.x;
    double s = 0.0, s2 = 0.0;
    for (int k = 0; k < 288; k++) {
        s  += (double)STp[k * 64 + oc];
        s2 += (double)STp[288 * 64 + k * 64 + oc];
    }
    double n = (double)(B * P);
    double mean = s / n;
    double var = s2 / n - mean * mean;
    float sc = gamma[oc] * rsqrtf((float)var + 1e-5f);
    scale[oc] = sc;
    shift[oc] = beta[oc] - (float)mean * sc;
}

// K7: recompute y, out = x + relu(y*scale+shift)
__launch_bounds__(256)
__global__ void k_fin2(const float* __restrict__ gmap, const float* __restrict__ U,
                       const float* __restrict__ x,
                       const float* __restrict__ scale, const float* __restrict__ shift,
                       float* __restrict__ out) {
    int tile = blockIdx.x, ocg = blockIdx.y, b = blockIdx.z;
    int ty0 = (tile / 6) * 32, tx0 = (tile % 6) * 32;
    __shared__ float h0[34 * 35], h1[34 * 35];
    stage_g(gmap, b, ty0, tx0, h0, h1);
    __syncthreads();

    int w = __builtin_amdgcn_readfirstlane(threadIdx.x >> 6);
    int lane = threadIdx.x & 63;
    int oc0 = ocg * 8 + w * 2;
    float u0[2][9], u1[2][9], sc[2], sh[2];
    #pragma unroll
    for (int j = 0; j < 2; j++) {
        const float* up = U + ((b * C + oc0 + j) * 2) * 9;
        #pragma unroll
        for (int t = 0; t < 9; t++) { u0[j][t] = up[t]; u1[j][t] = up[9 + t]; }
        sc[j] = scale[oc0 + j]; sh[j] = shift[oc0 + j];
    }
    for (int it = 0; it < 4; it++) {
        int row = it * 8 + (lane >> 3);
        int c0 = (lane & 7) * 4;
        float g0v[3][6], g1v[3][6];
        #pragma unroll
        for (int dy = 0; dy < 3; dy++)
            #pragma unroll
            for (int dx = 0; dx < 6; dx++) {
                g0v[dy][dx] = h0[(row + dy) * 35 + c0 + dx];
                g1v[dy][dx] = h1[(row + dy) * 35 + c0 + dx];
            }
        #pragma unroll
        for (int j = 0; j < 2; j++) {
            float y4[4];
            #pragma unroll
            for (int px = 0; px < 4; px++) {
                float y = 0.f;
                #pragma unroll
                for (int ky = 0; ky < 3; ky++)
                    #pragma unroll
                    for (int kx = 0; kx < 3; kx++) {
                        y += u0[j][ky * 3 + kx] * g0v[ky][px + kx];
                        y += u1[j][ky * 3 + kx] * g1v[ky][px + kx];
                    }
                y4[px] = y;
            }
            int ga = (b * C + oc0 + j) * P + (ty0 + row) * WWD + tx0 + c0;
            float4 xv = *(const float4*)(x + ga);
            float4 ov;
            ov.x = fmaxf(y4[0] * sc[j] + sh[j], 0.f) + xv.x;
            ov.y = fmaxf(y4[1] * sc[j] + sh[j], 0.f) + xv.y;
            ov.z = fmaxf(y4[2] * sc[j] + sh[j], 0.f) + xv.z;
            ov.w = fmaxf(y4[3] * sc[j] + sh[j], 0.f) + xv.w;
            *(float4*)(out + ga) = ov;
        }
    }
}

extern "C" void kernel_launch(void* const* d_in, const int* in_sizes, int n_in,
                              void* d_out, int out_size, void* d_ws, size_t ws_size,
                              hipStream_t stream) {
    const float* x     = (const float*)d_in[0];
    const float* cs    = (const float*)d_in[1];
    const float* Wc    = (const float*)d_in[2];
    const float* Wxs   = (const float*)d_in[3];
    const float* Wcsp  = (const float*)d_in[4];
    const float* Wcval = (const float*)d_in[5];
    const float* Wattn = (const float*)d_in[6];
    const float* Wcomb = (const float*)d_in[7];
    const float* Wsing = (const float*)d_in[8];
    const float* gamma = (const float*)d_in[9];
    const float* beta  = (const float*)d_in[10];
    float* ws  = (float*)d_ws;
    float* out = (float*)d_out;

    float* spp   = ws + OFF_SPACE;
    float* Wt    = ws + OFF_WT;      // overlays spp (dead after k_R2)
    float* gmap  = ws + OFF_GM;      // overlays spp (dead after k_R2)
    float* Spart = ws + OFF_SPART;
    float* R     = ws + OFF_R;
    float* tok2  = ws + OFF_TOK2;
    float* U     = ws + OFF_U;
    float* STp   = ws + OFF_STP;
    float* scale = ws + OFF_SCALE;
    float* shift = ws + OFF_SHIFT;

    // zero padded-space halos + R accumulator + tok2 accumulator (contiguous range)
    hipMemsetAsync(ws, 0, (size_t)(OFF_TOK2 + 1024) * sizeof(float), stream);

    k_space<<<dim3(144, 16), 256, 0, stream>>>(cs, Wc, spp, Spart);
    k_R2   <<<dim3(4, 64, 4), 256, 0, stream>>>(x, spp, R);
    k_wt   <<<dim3(576, 8), 64, 0, stream>>>(Wxs, Wt);           // spp dead from here
    k_g    <<<dim3(144, 16), 256, 0, stream>>>(cs, Wcval, Wattn, Wcomb, gmap);
    k_tok2 <<<dim3(16, 8), 64, 0, stream>>>(Wt, Wcsp, R, Spart, tok2);
    k_U    <<<dim3(8, 2), 64, 0, stream>>>(Wsing, tok2, U);
    k_cs   <<<dim3(36, 8, 8), 256, 0, stream>>>(gmap, U, STp);
    k_bnfin<<<1, 64, 0, stream>>>(STp, gamma, beta, scale, shift);
    k_fin2 <<<dim3(36, 8, 8), 256, 0, stream>>>(gmap, U, x, scale, shift, out);
}

// Round 9
// 380.156 us; speedup vs baseline: 10.0960x; 1.5220x over previous
//
#include <hip/hip_runtime.h>
#include <math.h>

// Problem constants (fixed by reference setup_inputs)
#define B   8
#define C   64
#define HH  192
#define WWD 192
#define P   (HH*WWD)     // 36864
#define NC  2
#define NS  8
#define PP  (194*194)    // padded space map (1-px zero halo), 37636

// Workspace layout (float offsets)
#define OFF_SPACE 0                    // 128 maps * PP = 4817408 (zero-padded)
// Wt, gmap, WsT REUSE the spp region (dead after k_R2).
#define OFF_WT    0                    // 8*576*64 = 294912 transposed Wxs
#define OFF_GM    294912               // 8*2*P = 589824 combined attention maps
#define OFF_WST   884736               // 64*9*64 = 36864 transposed Wsing [ci][t][oc]
#define OFF_SPART 4817408              // 128*144 per-block S partials
#define OFF_R     4835840              // 8*16*64*9 = 73728 correlations (zeroed; k_R2 accumulates)
#define OFF_TOK2  4909568              // 8*2*64 = 1024 (atomic accumulated, needs zero)
#define OFF_U     4910592              // 8*64*2*9 = 9216 collapsed conv weights
#define OFF_STP   4919808              // 2*64*288 BN partial sums ([slot][oc] major)
#define OFF_SCALE 4956672              // 64
#define OFF_SHIFT 4956736              // 64
#define WS_FLOATS 4956800              // ~19.8 MB total

__device__ __forceinline__ float sigm(float x) { return 1.0f / (1.0f + expf(-x)); }

// K1: space maps (sigmoid + 1->7 ch 3x3 conv + sigmoid) into zero-padded layout,
// plus per-(map,ch) per-block partial sums (NO global atomics).
__global__ void k_space(const float* __restrict__ cs, const float* __restrict__ Wc,
                        float* __restrict__ spp, float* __restrict__ Spart) {
    int m = blockIdx.y;                       // m = b*2 + c
    int bx = blockIdx.x;
    int p = bx * 256 + threadIdx.x;           // 144*256 == P exactly
    int h = p / WWD, w = p - (p / WWD) * WWD;
    float cp[9];
    #pragma unroll
    for (int ky = 0; ky < 3; ky++)
        #pragma unroll
        for (int kx = 0; kx < 3; kx++) {
            int hh = h + ky - 1, ww = w + kx - 1;
            float v = 0.f;  // zero-pad AFTER sigmoid (conv pads class_prob with 0)
            if ((unsigned)hh < HH && (unsigned)ww < WWD)
                v = sigm(cs[m * P + hh * WWD + ww]);
            cp[ky * 3 + kx] = v;
        }
    float ch[8];
    ch[0] = cp[4];
    #pragma unroll
    for (int j = 0; j < 7; j++) {
        float a = 0.f;
        #pragma unroll
        for (int k = 0; k < 9; k++) a += Wc[j * 9 + k] * cp[k];
        ch[j + 1] = sigm(a);
    }
    #pragma unroll
    for (int q = 0; q < 8; q++)
        spp[(m * 8 + q) * PP + (h + 1) * 194 + (w + 1)] = ch[q];
    // per-wave shfl reduce -> LDS -> per-block partial (no atomics)
    __shared__ float red[4][8];
    int lane = threadIdx.x & 63, wave = threadIdx.x >> 6;
    #pragma unroll
    for (int q = 0; q < 8; q++) {
        float v = ch[q];
        for (int off = 32; off > 0; off >>= 1) v += __shfl_down(v, off);
        if (lane == 0) red[wave][q] = v;
    }
    __syncthreads();
    if (threadIdx.x < 8) {
        int q = threadIdx.x;
        Spart[(m * 8 + q) * 144 + bx] = red[0][q] + red[1][q] + red[2][q] + red[3][q];
    }
}

// K2: register-tiled correlation, one space map x 8 x-channels per block.
// FROZEN at the R5 form (187us, 84 VGPR, no spill). Four restructure attempts
// (2-map acc, reg double-buffer, shfl-share, LDS-share) all spilled or re-sank:
// this compiler will not hold >~90 live VGPRs in this loop. Do not touch.
__launch_bounds__(256, 3)
__global__ void k_R2(const float* __restrict__ x, const float* __restrict__ spp,
                     float* __restrict__ R) {
    int ig = blockIdx.x;    // 0..7 : i = ig*8 + il
    int scz = blockIdx.y;   // 0..31 : sc = scz & 15, half = scz >> 4
    int b  = blockIdx.z;
    int sc = scz & 15;
    int half = scz >> 4;
    int s = sc >> 1, c = sc & 1;
    const float* xb = x + (b * C + ig * 8) * P;
    const float* sp = spp + ((b * NC + c) * NS + s) * PP;

    float acc[8][9];
    #pragma unroll
    for (int i = 0; i < 8; i++)
        #pragma unroll
        for (int t = 0; t < 9; t++) acc[i][t] = 0.f;

    for (int it = half * 18; it < half * 18 + 18; it++) {
        int p0 = it * 1024 + threadIdx.x * 4;
        int h = p0 / WWD, w0 = p0 - (p0 / WWD) * WWD;
        float4 xv[8];
        #pragma unroll
        for (int i = 0; i < 8; i++) xv[i] = *(const float4*)(xb + i * P + p0);
        float g[3][6];
        #pragma unroll
        for (int ty = 0; ty < 3; ty++) {
            const float* rp = sp + (h + 2 - ty) * 194 + w0;
            float4 ga; float2 gb;
            __builtin_memcpy(&ga, rp, 16);
            __builtin_memcpy(&gb, rp + 4, 8);
            g[ty][0] = ga.x; g[ty][1] = ga.y; g[ty][2] = ga.z;
            g[ty][3] = ga.w; g[ty][4] = gb.x; g[ty][5] = gb.y;
        }
        #pragma unroll
        for (int ty = 0; ty < 3; ty++)
            #pragma unroll
            for (int tx = 0; tx < 3; tx++) {
                float g0 = g[ty][2 - tx], g1 = g[ty][3 - tx];
                float g2 = g[ty][4 - tx], g3 = g[ty][5 - tx];
                #pragma unroll
                for (int i = 0; i < 8; i++) {
                    float a = acc[i][ty * 3 + tx];
                    a += xv[i].x * g0; a += xv[i].y * g1;
                    a += xv[i].z * g2; a += xv[i].w * g3;
                    acc[i][ty * 3 + tx] = a;
                }
            }
    }

    __shared__ float red[4][72];
    int lane = threadIdx.x & 63, wave = threadIdx.x >> 6;
    #pragma unroll
    for (int i = 0; i < 8; i++)
        #pragma unroll
        for (int t = 0; t < 9; t++) {
            float v = acc[i][t];
            for (int off = 32; off > 0; off >>= 1) v += __shfl_down(v, off);
            if (lane == 0) red[wave][i * 9 + t] = v;
        }
    __syncthreads();
    if (threadIdx.x < 72) {
        int i = threadIdx.x / 9, t = threadIdx.x - (threadIdx.x / 9) * 9;
        float v = red[0][threadIdx.x] + red[1][threadIdx.x] +
                  red[2][threadIdx.x] + red[3][threadIdx.x];
        atomicAdd(&R[((b * 16 + sc) * 64 + (ig * 8 + i)) * 9 + t], v);
    }
}

// K2b: BOTH weight transposes in one launch (flat grid, branch on block range).
// blocks [0,1152): Wt[(s*576+t)*64+d] = Wxs[(s*64+d)*576+t]   (294912 elems)
// blocks [1152,1296): WsT[ci*576 + t*64 + oc] = Ws[(oc*64+ci)*9+t] (36864 elems)
__global__ void k_wtb(const float* __restrict__ Wxs, const float* __restrict__ Ws,
                      float* __restrict__ Wt, float* __restrict__ WsT) {
    int blk = blockIdx.x;
    if (blk < 1152) {
        int o = blk * 256 + threadIdx.x;          // output-coalesced
        int d = o & 63, r = o >> 6;               // r = s*576+t
        int s = r / 576, t = r - s * 576;
        Wt[o] = Wxs[(s * 64 + d) * 576 + t];
    } else {
        int o = (blk - 1152) * 256 + threadIdx.x; // output-coalesced
        int ci = o / 576, q = o - ci * 576;
        int t = q >> 6, oc = q & 63;
        WsT[o] = Ws[(oc * 64 + ci) * 9 + t];
    }
}

// K2c: combined attention map gmap[b][cl][p] = sum_s Wcomb[s]*Wcval[s]*sigm(sigm(cs)*Wattn[s])
__global__ void k_g(const float* __restrict__ cs, const float* __restrict__ Wcval,
                    const float* __restrict__ Wattn, const float* __restrict__ Wcomb,
                    float* __restrict__ gmap) {
    int m = blockIdx.y;                       // b*2 + cl
    int p = blockIdx.x * 256 + threadIdx.x;   // 144*256 == P
    float wa[8], wt[8];
    #pragma unroll
    for (int s = 0; s < 8; s++) { wa[s] = Wcomb[s] * Wcval[s]; wt[s] = Wattn[s]; }
    float cp = sigm(cs[m * P + p]);
    float a = 0.f;
    #pragma unroll
    for (int s = 0; s < 8; s++) a += wa[s] * sigm(cp * wt[s]);
    gmap[m * P + p] = a;
}

// K3: tok2[b,c,d] = sum_s Wcs[s]/S[b,c,s] * sum_t Wt[s][t][d] * R[b,s,c,t]
// K-split x4 over t (blockIdx.z); partial sums atomicAdd (tok2 pre-zeroed).
// 512 single-wave blocks -> 2 waves/CU instead of 0.5.
__global__ void k_tok2(const float* __restrict__ Wt, const float* __restrict__ Wcs,
                       const float* __restrict__ R, const float* __restrict__ Spart,
                       float* __restrict__ tok2) {
    int bc = blockIdx.x, s = blockIdx.y, tz = blockIdx.z;
    int d = threadIdx.x;
    const float* spp = Spart + (bc * 8 + s) * 144;
    float sv = 0.f;
    for (int k = d; k < 144; k += 64) sv += spp[k];
    #pragma unroll
    for (int msk = 32; msk >= 1; msk >>= 1) sv += __shfl_xor(sv, msk);

    const float* Rp = R + ((bc & 1) + ((bc >> 1) * 16 + s * 2)) * 576;
    const float* Wp = Wt + s * 576 * 64 + d;
    float a = 0.f;
    int t0 = tz * 144;
    #pragma unroll 8
    for (int t = t0; t < t0 + 144; t++) a += Wp[t * 64] * Rp[t];
    float val = a * Wcs[s] / sv;
    atomicAdd(&tok2[bc * C + d], val);
}

// K4: U[b][oc][m][t] = sum_ci Ws[oc,ci,t]*tok2[b,m,ci], via transposed WsT[ci][t][oc].
// Block 576 threads (tid = t*64+oc): reads WsT[ci*576+tid] fully coalesced; tok in LDS.
__global__ void k_U(const float* __restrict__ WsT, const float* __restrict__ tok2,
                    float* __restrict__ U) {
    int b = blockIdx.x, m = blockIdx.y;
    int tid = threadIdx.x;                 // 0..575
    int oc = tid & 63, t = tid >> 6;
    __shared__ float tok[64];
    if (tid < 64) tok[tid] = tok2[(b * NC + m) * C + tid];
    __syncthreads();
    float a = 0.f;
    #pragma unroll 8
    for (int ci = 0; ci < C; ci++) a += WsT[ci * 576 + tid] * tok[ci];
    U[((b * C + oc) * 2 + m) * 9 + t] = a;
}

// Shared staging: g0/g1 34x34 halo tiles from precomputed gmap (pure coalesced copy).
__device__ __forceinline__ void stage_g(const float* __restrict__ gmap, int b, int ty0, int tx0,
                                        float* h0, float* h1) {
    const float* g0p = gmap + (b * NC + 0) * P;
    const float* g1p = gmap + (b * NC + 1) * P;
    for (int idx = threadIdx.x; idx < 34 * 34; idx += 256) {
        int i = idx / 34, j = idx - (idx / 34) * 34;
        int gy = ty0 - 1 + i, gx = tx0 - 1 + j;
        float a0 = 0.f, a1 = 0.f;
        if ((unsigned)gy < HH && (unsigned)gx < WWD) {
            int p = gy * WWD + gx;
            a0 = g0p[p]; a1 = g1p[p];
        }
        h0[i * 35 + j] = a0; h1[i * 35 + j] = a1;
    }
}

// K5: BN partials. Stage tile ONCE, loop 4 ocg groups over it (was 8 blocks
// re-staging the same tile). Grid (36, 2, 8) = 576 blocks.
__launch_bounds__(256)
__global__ void k_cs(const float* __restrict__ gmap, const float* __restrict__ U,
                     float* __restrict__ STp) {
    int tile = blockIdx.x, og2 = blockIdx.y, b = blockIdx.z;
    int ty0 = (tile / 6) * 32, tx0 = (tile % 6) * 32;
    __shared__ float h0[34 * 35], h1[34 * 35];
    stage_g(gmap, b, ty0, tx0, h0, h1);
    __syncthreads();

    int w = __builtin_amdgcn_readfirstlane(threadIdx.x >> 6);
    int lane = threadIdx.x & 63;
    for (int g4 = 0; g4 < 4; g4++) {
        int oc0 = (og2 * 4 + g4) * 8 + w * 2;
        float u0[2][9], u1[2][9];
        #pragma unroll
        for (int j = 0; j < 2; j++) {
            const float* up = U + ((b * C + oc0 + j) * 2) * 9;
            #pragma unroll
            for (int t = 0; t < 9; t++) { u0[j][t] = up[t]; u1[j][t] = up[9 + t]; }
        }
        float s1[2] = {0.f, 0.f}, s2[2] = {0.f, 0.f};
        for (int it = 0; it < 4; it++) {
            int row = it * 8 + (lane >> 3);
            int c0 = (lane & 7) * 4;
            float g0v[3][6], g1v[3][6];
            #pragma unroll
            for (int dy = 0; dy < 3; dy++)
                #pragma unroll
                for (int dx = 0; dx < 6; dx++) {
                    g0v[dy][dx] = h0[(row + dy) * 35 + c0 + dx];
                    g1v[dy][dx] = h1[(row + dy) * 35 + c0 + dx];
                }
            #pragma unroll
            for (int j = 0; j < 2; j++)
                #pragma unroll
                for (int px = 0; px < 4; px++) {
                    float y = 0.f;
                    #pragma unroll
                    for (int ky = 0; ky < 3; ky++)
                        #pragma unroll
                        for (int kx = 0; kx < 3; kx++) {
                            y += u0[j][ky * 3 + kx] * g0v[ky][px + kx];
                            y += u1[j][ky * 3 + kx] * g1v[ky][px + kx];
                        }
                    s1[j] += y; s2[j] += y * y;
                }
        }
        #pragma unroll
        for (int j = 0; j < 2; j++) {
            float a = s1[j], q = s2[j];
            for (int off = 32; off > 0; off >>= 1) { a += __shfl_down(a, off); q += __shfl_down(q, off); }
            if (lane == 0) {
                int slot = b * 36 + tile;
                STp[slot * 64 + (oc0 + j)] = a;
                STp[288 * 64 + slot * 64 + (oc0 + j)] = q;
            }
        }
    }
}

// K6: finalize BN scale/shift. 256 threads (4-way k-split + LDS combine).
__global__ void k_bnfin(const float* __restrict__ STp, const float* __restrict__ gamma,
                        const float* __restrict__ beta, float* __restrict__ scale,
                        float* __restrict__ shift) {
    int oc = threadIdx.x & 63, q = threadIdx.x >> 6;
    double s = 0.0, s2 = 0.0;
    for (int k = q * 72; k < q * 72 + 72; k++) {
        s  += (double)STp[k * 64 + oc];
        s2 += (double)STp[288 * 64 + k * 64 + oc];
    }
    __shared__ double ls[4][64], ls2[4][64];
    ls[q][oc] = s; ls2[q][oc] = s2;
    __syncthreads();
    if (threadIdx.x < 64) {
        double S  = ls[0][oc] + ls[1][oc] + ls[2][oc] + ls[3][oc];
        double S2 = ls2[0][oc] + ls2[1][oc] + ls2[2][oc] + ls2[3][oc];
        double n = (double)(B * P);
        double mean = S / n;
        double var = S2 / n - mean * mean;
        float sc = gamma[oc] * rsqrtf((float)var + 1e-5f);
        scale[oc] = sc;
        shift[oc] = beta[oc] - (float)mean * sc;
    }
}

// K7: out = x + relu(y*scale+shift). Stage tile once, loop 4 ocg groups.
__launch_bounds__(256)
__global__ void k_fin2(const float* __restrict__ gmap, const float* __restrict__ U,
                       const float* __restrict__ x,
                       const float* __restrict__ scale, const float* __restrict__ shift,
                       float* __restrict__ out) {
    int tile = blockIdx.x, og2 = blockIdx.y, b = blockIdx.z;
    int ty0 = (tile / 6) * 32, tx0 = (tile % 6) * 32;
    __shared__ float h0[34 * 35], h1[34 * 35];
    stage_g(gmap, b, ty0, tx0, h0, h1);
    __syncthreads();

    int w = __builtin_amdgcn_readfirstlane(threadIdx.x >> 6);
    int lane = threadIdx.x & 63;
    for (int g4 = 0; g4 < 4; g4++) {
        int oc0 = (og2 * 4 + g4) * 8 + w * 2;
        float u0[2][9], u1[2][9], sc[2], sh[2];
        #pragma unroll
        for (int j = 0; j < 2; j++) {
            const float* up = U + ((b * C + oc0 + j) * 2) * 9;
            #pragma unroll
            for (int t = 0; t < 9; t++) { u0[j][t] = up[t]; u1[j][t] = up[9 + t]; }
            sc[j] = scale[oc0 + j]; sh[j] = shift[oc0 + j];
        }
        for (int it = 0; it < 4; it++) {
            int row = it * 8 + (lane >> 3);
            int c0 = (lane & 7) * 4;
            float g0v[3][6], g1v[3][6];
            #pragma unroll
            for (int dy = 0; dy < 3; dy++)
                #pragma unroll
                for (int dx = 0; dx < 6; dx++) {
                    g0v[dy][dx] = h0[(row + dy) * 35 + c0 + dx];
                    g1v[dy][dx] = h1[(row + dy) * 35 + c0 + dx];
                }
            #pragma unroll
            for (int j = 0; j < 2; j++) {
                float y4[4];
                #pragma unroll
                for (int px = 0; px < 4; px++) {
                    float y = 0.f;
                    #pragma unroll
                    for (int ky = 0; ky < 3; ky++)
                        #pragma unroll
                        for (int kx = 0; kx < 3; kx++) {
                            y += u0[j][ky * 3 + kx] * g0v[ky][px + kx];
                            y += u1[j][ky * 3 + kx] * g1v[ky][px + kx];
                        }
                    y4[px] = y;
                }
                int ga = (b * C + oc0 + j) * P + (ty0 + row) * WWD + tx0 + c0;
                float4 xv = *(const float4*)(x + ga);
                float4 ov;
                ov.x = fmaxf(y4[0] * sc[j] + sh[j], 0.f) + xv.x;
                ov.y = fmaxf(y4[1] * sc[j] + sh[j], 0.f) + xv.y;
                ov.z = fmaxf(y4[2] * sc[j] + sh[j], 0.f) + xv.z;
                ov.w = fmaxf(y4[3] * sc[j] + sh[j], 0.f) + xv.w;
                *(float4*)(out + ga) = ov;
            }
        }
    }
}

extern "C" void kernel_launch(void* const* d_in, const int* in_sizes, int n_in,
                              void* d_out, int out_size, void* d_ws, size_t ws_size,
                              hipStream_t stream) {
    const float* x     = (const float*)d_in[0];
    const float* cs    = (const float*)d_in[1];
    const float* Wc    = (const float*)d_in[2];
    const float* Wxs   = (const float*)d_in[3];
    const float* Wcsp  = (const float*)d_in[4];
    const float* Wcval = (const float*)d_in[5];
    const float* Wattn = (const float*)d_in[6];
    const float* Wcomb = (const float*)d_in[7];
    const float* Wsing = (const float*)d_in[8];
    const float* gamma = (const float*)d_in[9];
    const float* beta  = (const float*)d_in[10];
    float* ws  = (float*)d_ws;
    float* out = (float*)d_out;

    float* spp   = ws + OFF_SPACE;
    float* Wt    = ws + OFF_WT;      // overlays spp (dead after k_R2)
    float* gmap  = ws + OFF_GM;      // overlays spp (dead after k_R2)
    float* WsT   = ws + OFF_WST;     // overlays spp (dead after k_R2)
    float* Spart = ws + OFF_SPART;
    float* R     = ws + OFF_R;
    float* tok2  = ws + OFF_TOK2;
    float* U     = ws + OFF_U;
    float* STp   = ws + OFF_STP;
    float* scale = ws + OFF_SCALE;
    float* shift = ws + OFF_SHIFT;

    // zero padded-space halos + R accumulator + tok2 accumulator (contiguous range)
    hipMemsetAsync(ws, 0, (size_t)(OFF_TOK2 + 1024) * sizeof(float), stream);

    k_space<<<dim3(144, 16), 256, 0, stream>>>(cs, Wc, spp, Spart);
    k_R2   <<<dim3(8, 32, 8), 256, 0, stream>>>(x, spp, R);
    k_wtb  <<<dim3(1296), 256, 0, stream>>>(Wxs, Wsing, Wt, WsT);  // spp dead from here
    k_g    <<<dim3(144, 16), 256, 0, stream>>>(cs, Wcval, Wattn, Wcomb, gmap);
    k_tok2 <<<dim3(16, 8, 4), 64, 0, stream>>>(Wt, Wcsp, R, Spart, tok2);
    k_U    <<<dim3(8, 2), 576, 0, stream>>>(WsT, tok2, U);
    k_cs   <<<dim3(36, 2, 8), 256, 0, stream>>>(gmap, U, STp);
    k_bnfin<<<1, 256, 0, stream>>>(STp, gamma, beta, scale, shift);
    k_fin2 <<<dim3(36, 2, 8), 256, 0, stream>>>(gmap, U, x, scale, shift, out);
}